// Round 1
// 516.644 us; speedup vs baseline: 1.0305x; 1.0305x over previous
//
#include <hip/hip_runtime.h>
#include <hip/hip_bf16.h>
#include <stdint.h>

typedef __attribute__((ext_vector_type(8))) short bf16x8;   // 8 bf16 = 4 VGPRs
typedef __attribute__((ext_vector_type(4))) float f32x4;

__device__ __forceinline__ unsigned short f2bf(float f) {
    unsigned u = __builtin_bit_cast(unsigned, f);
    u += 0x7FFF + ((u >> 16) & 1);        // RNE (finite inputs)
    return (unsigned short)(u >> 16);
}
__device__ __forceinline__ float bf2f(unsigned short h) {
    return __builtin_bit_cast(float, (unsigned)h << 16);
}
__device__ __forceinline__ void load_lds16(const void* g, void* l) {
    __builtin_amdgcn_global_load_lds(
        (const __attribute__((address_space(1))) void*)g,
        (__attribute__((address_space(3))) void*)l, 16, 0, 0);
}

// ---------------------------------------------------------------------------
// fp32 -> bf16 bulk convert. n divisible by 2048; one thread = 8 elems.
// ---------------------------------------------------------------------------
__global__ __launch_bounds__(256)
void cvt_kernel(const float* __restrict__ src, unsigned short* __restrict__ dst)
{
    const long i = ((long)blockIdx.x * 256 + threadIdx.x) * 8;
    const float4 a = *(const float4*)(src + i);
    const float4 b = *(const float4*)(src + i + 4);
    bf16x8 r;
    r[0] = (short)f2bf(a.x); r[1] = (short)f2bf(a.y);
    r[2] = (short)f2bf(a.z); r[3] = (short)f2bf(a.w);
    r[4] = (short)f2bf(b.x); r[5] = (short)f2bf(b.y);
    r[6] = (short)f2bf(b.z); r[7] = (short)f2bf(b.w);
    *(bf16x8*)(dst + i) = r;
}

// ---------------------------------------------------------------------------
// C[m,n] = sum_k A[m,k]*Bt[n,k], K=1024, bf16, K-contiguous.
// 256x256 tile, 8 waves (2M x 4N), per-wave 128x64, BK=64, 8-phase schedule
// (T3+T4 counted vmcnt + T5 setprio). LDS 128 KiB: [buf][A0,A1,B0,B1][128x64].
// Conflict-free XOR-chunk swizzle: LDS chunk c of row r holds global chunk
// c^(r&7); staged via pre-swizzled global src (global_load_lds dest linear).
// Stage stream per iter (2 K-tiles): ph1,2: t(2i+1) A0,A1 -> buf1;
// ph3..6: t(2i+2) B0,B1,A0,A1 -> buf0; ph7,8: t(2i+3) B0,B1 -> buf1.
// B-halves of a tile are fully read after its local ph2, A-halves after ph3,
// so every stage lands in a region already retired by a barrier.
// vmcnt(4)=2 half-tiles in flight at ph4/ph8 checkpoints; never 0 in loop.
// MODE 0: relu+0.125 on q,k; scatter bf16 q/k/v. MODE 1: +bias, fp32 out.
// ---------------------------------------------------------------------------
#define LD_A(p, i, s) (*(const bf16x8*)&lds[p][wr][((i) * 16 + fr) * 64 + ((((s) << 2) + qd) ^ cx) * 8])
#define LD_B(p, j, s) (*(const bf16x8*)&lds[p][2 + bh_][(brow_ + (j) * 16 + fr) * 64 + ((((s) << 2) + qd) ^ cx) * 8])

#define LDA4(p, ib) do { \
    afr[0][0] = LD_A(p, (ib)+0, 0); afr[0][1] = LD_A(p, (ib)+0, 1); \
    afr[1][0] = LD_A(p, (ib)+1, 0); afr[1][1] = LD_A(p, (ib)+1, 1); \
    afr[2][0] = LD_A(p, (ib)+2, 0); afr[2][1] = LD_A(p, (ib)+2, 1); \
    afr[3][0] = LD_A(p, (ib)+3, 0); afr[3][1] = LD_A(p, (ib)+3, 1); \
} while (0)

#define LDB2(p, jb) do { \
    bfr[(jb)+0][0] = LD_B(p, (jb)+0, 0); bfr[(jb)+0][1] = LD_B(p, (jb)+0, 1); \
    bfr[(jb)+1][0] = LD_B(p, (jb)+1, 0); bfr[(jb)+1][1] = LD_B(p, (jb)+1, 1); \
} while (0)

#define STAGE_A(p, half, tile) do { \
    const unsigned short* s_ = Ag + (long)((half) * 128) * 1024 + (tile) * 64; \
    unsigned short* d_ = ldsw + ((p) * 4 + (half)) * 8192; \
    load_lds16(s_, d_); \
    load_lds16(s_ + (long)64 * 1024, d_ + 4096); \
} while (0)

#define STAGE_B(p, half, tile) do { \
    const unsigned short* s_ = Bg + (long)((half) * 128) * 1024 + (tile) * 64; \
    unsigned short* d_ = ldsw + ((p) * 4 + 2 + (half)) * 8192; \
    load_lds16(s_, d_); \
    load_lds16(s_ + (long)64 * 1024, d_ + 4096); \
} while (0)

#define MM(ib, jb) do { \
    _Pragma("unroll") \
    for (int i_ = 0; i_ < 4; ++i_) { \
        acc[(ib)+i_][(jb)+0] = __builtin_amdgcn_mfma_f32_16x16x32_bf16(afr[i_][0], bfr[(jb)+0][0], acc[(ib)+i_][(jb)+0], 0, 0, 0); \
        acc[(ib)+i_][(jb)+1] = __builtin_amdgcn_mfma_f32_16x16x32_bf16(afr[i_][0], bfr[(jb)+1][0], acc[(ib)+i_][(jb)+1], 0, 0, 0); \
    } \
    _Pragma("unroll") \
    for (int i_ = 0; i_ < 4; ++i_) { \
        acc[(ib)+i_][(jb)+0] = __builtin_amdgcn_mfma_f32_16x16x32_bf16(afr[i_][1], bfr[(jb)+0][1], acc[(ib)+i_][(jb)+0], 0, 0, 0); \
        acc[(ib)+i_][(jb)+1] = __builtin_amdgcn_mfma_f32_16x16x32_bf16(afr[i_][1], bfr[(jb)+1][1], acc[(ib)+i_][(jb)+1], 0, 0, 0); \
    } \
} while (0)

#define PH_MID() do { \
    __builtin_amdgcn_sched_barrier(0); \
    __builtin_amdgcn_s_barrier(); \
    asm volatile("s_waitcnt lgkmcnt(0)" ::: "memory"); \
    __builtin_amdgcn_sched_barrier(0); \
    __builtin_amdgcn_s_setprio(1); \
} while (0)

#define PH_END() do { \
    __builtin_amdgcn_s_setprio(0); \
    __builtin_amdgcn_s_barrier(); \
} while (0)

#define PH_END_V(n) do { \
    __builtin_amdgcn_s_setprio(0); \
    asm volatile("s_waitcnt vmcnt(" #n ")" ::: "memory"); \
    __builtin_amdgcn_s_barrier(); \
} while (0)

template<int MODE>
__global__ __launch_bounds__(512, 2)
void gemm_bt_kernel(const unsigned short* __restrict__ A,
                    const unsigned short* __restrict__ Bt,
                    __hip_bfloat16* __restrict__ o0,
                    __hip_bfloat16* __restrict__ o1,
                    __hip_bfloat16* __restrict__ o2,
                    float* __restrict__ outf,
                    const float* __restrict__ bias)
{
    constexpr int K  = 1024;
    constexpr int NT = (MODE == 0) ? 12 : 4;
    __shared__ __attribute__((aligned(16))) unsigned short lds[2][4][8192]; // 128 KiB

    // group-major swizzle: 8 m-tiles share B-tiles among co-resident blocks
    const int bid   = blockIdx.x;
    const int npg   = 8 * NT;
    const int group = bid / npg;
    const int rem   = bid - group * npg;
    const int gm    = (98 - group * 8 < 8) ? (98 - group * 8) : 8;
    const int mt    = group * 8 + rem % gm;
    const int nt    = rem / gm;
    const long m0 = (long)mt * 256;
    const long n0 = (long)nt * 256;

    const int t    = threadIdx.x;
    const int lane = t & 63;
    const int wv   = t >> 6;
    const int wr   = wv >> 2;        // 0..1 (M half)
    const int wc   = wv & 3;         // 0..3 (N quarter)
    const int fr   = lane & 15;
    const int qd   = lane >> 4;
    const int cx   = fr & 7;
    const int bh_   = wc >> 1;       // B half index
    const int brow_ = (wc & 1) << 6; // row base within B half

    // staging: 512 thr x 16B = 64 rows/issue; thread t -> row t>>3, LDS chunk
    // t&7 holding global chunk (t&7)^(row&7). LDS dest wave-uniform+lane*16.
    const int srow = t >> 3;                 // 0..63
    const int gch  = (t & 7) ^ (srow & 7);
    const unsigned short* Ag = A  + (m0 + srow) * K + gch * 8;
    const unsigned short* Bg = Bt + (n0 + srow) * K + gch * 8;
    unsigned short* const ldsw = &lds[0][0][0] + wv * 512;   // wave base (ushorts)

    f32x4 acc[8][4] = {};
    bf16x8 afr[4][2], bfr[4][2];

    // prologue: tile0 (buf0) fully + tile1 B0,B1 (buf1) in flight
    STAGE_B(0, 0, 0); STAGE_B(0, 1, 0); STAGE_A(0, 0, 0); STAGE_A(0, 1, 0);
    STAGE_B(1, 0, 1); STAGE_B(1, 1, 1);
    asm volatile("s_waitcnt vmcnt(4)" ::: "memory");
    __builtin_amdgcn_s_barrier();

#pragma unroll 1
    for (int it = 0; it < 7; ++it) {
        const int t1 = 2 * it + 1, t2 = 2 * it + 2, t3 = 2 * it + 3;
        // ---- K-tile 2it (buf0) ----
        LDA4(0, 0); LDB2(0, 0); STAGE_A(1, 0, t1);        // ph1 (12 ds_read)
        PH_MID(); MM(0, 0); PH_END();
        LDB2(0, 2); STAGE_A(1, 1, t1);                    // ph2 (4)
        PH_MID(); MM(0, 2); PH_END();
        LDA4(0, 4); STAGE_B(0, 0, t2);                    // ph3 (8)
        PH_MID(); MM(4, 0); PH_END();
        STAGE_B(0, 1, t2);                                // ph4 (0) + checkpoint
        PH_MID(); MM(4, 2); PH_END_V(4);
        // ---- K-tile 2it+1 (buf1) ----
        LDA4(1, 0); LDB2(1, 0); STAGE_A(0, 0, t2);        // ph5
        PH_MID(); MM(0, 0); PH_END();
        LDB2(1, 2); STAGE_A(0, 1, t2);                    // ph6
        PH_MID(); MM(0, 2); PH_END();
        LDA4(1, 4); STAGE_B(1, 0, t3);                    // ph7
        PH_MID(); MM(4, 0); PH_END();
        STAGE_B(1, 1, t3);                                // ph8 + checkpoint
        PH_MID(); MM(4, 2); PH_END_V(4);
    }
    // ---- peeled last iteration: tiles 14 (buf0), 15 (buf1); no new stages ----
    LDA4(0, 0); LDB2(0, 0); STAGE_A(1, 0, 15);
    PH_MID(); MM(0, 0); PH_END();
    LDB2(0, 2); STAGE_A(1, 1, 15);
    PH_MID(); MM(0, 2); PH_END();
    LDA4(0, 4);
    PH_MID(); MM(4, 0); PH_END();
    PH_MID(); MM(4, 2); PH_END_V(0);   // drain: tile15 A0,A1 must land
    LDA4(1, 0); LDB2(1, 0);
    PH_MID(); MM(0, 0); PH_END();
    LDB2(1, 2);
    PH_MID(); MM(0, 2); PH_END();
    LDA4(1, 4);
    PH_MID(); MM(4, 0); PH_END();
    __builtin_amdgcn_s_barrier();
    asm volatile("s_waitcnt lgkmcnt(0)" ::: "memory");
    __builtin_amdgcn_sched_barrier(0);
    __builtin_amdgcn_s_setprio(1); MM(4, 2); __builtin_amdgcn_s_setprio(0);

    // C/D layout: col = fr, row = qd*4 + reg. Wave tile: rows wr*128+, cols wc*64+.
    if (MODE == 0) {
        const int which = nt >> 2;  // 0:q 1:k 2:v (each 1024 cols = 4 n-tiles)
        __hip_bfloat16* dst = (which == 0) ? o0 : (which == 1) ? o1 : o2;
        const int colbase = ((nt & 3) << 8) + wc * 64;
        const bool act = (which < 2);
#pragma unroll
        for (int i = 0; i < 8; ++i) {
            const long mrow = m0 + wr * 128 + i * 16 + qd * 4;
#pragma unroll
            for (int r = 0; r < 4; ++r) {
                const long moff = (mrow + r) * 1024;
#pragma unroll
                for (int j = 0; j < 4; ++j) {
                    float v = acc[i][j][r];
                    if (act) v = fmaxf(v, 0.f) + 0.125f;
                    dst[moff + colbase + j * 16 + fr] = __float2bfloat16(v);
                }
            }
        }
    } else {
        const long nbase = n0 + wc * 64;
#pragma unroll
        for (int i = 0; i < 8; ++i) {
            const long mrow = m0 + wr * 128 + i * 16 + qd * 4;
#pragma unroll
            for (int r = 0; r < 4; ++r) {
                const long moff = (mrow + r) * 1024;
#pragma unroll
                for (int j = 0; j < 4; ++j)
                    outf[moff + nbase + j * 16 + fr] =
                        acc[i][j][r] + bias[nbase + j * 16 + fr];
            }
        }
    }
}

// ---------------------------------------------------------------------------
// Phase 2: kv[bh,e,d] partials over n, 14-way split (224 rows each).
// Block = (bb, h-octet, sp); 256 thr = 8 h-sub x (8 e-blk x 4 d-blk).
// Thread: 8e x 16d register tile -> FMA-bound (128 FMA per 6 ds_read_b128).
// kvp written in MFMA-B-FRAGMENT order: [sp][bh][(s2*4+j)*64+lane][jj],
// elem = kv[e = s2*32+(lane>>4)*8+jj][d = j*16+(lane&15)].
// ---------------------------------------------------------------------------
__global__ __launch_bounds__(256)
void kv_partial_kernel(const __hip_bfloat16* __restrict__ kbuf,
                       const __hip_bfloat16* __restrict__ vbuf,
                       float* __restrict__ kvp,    // [14][128][4096] frag-order
                       float* __restrict__ ksump)  // [14][128][64]
{
    __shared__ float kf[8][512];
    __shared__ float vf[8][512];
    const int t   = threadIdx.x;
    const int bid = blockIdx.x;
    const int sp   = bid % 14;
    const int hoct = (bid / 14) & 1;
    const int bb   = bid / 28;
    const long rowstart = (long)bb * 3136 + sp * 224;

    const int hsub = t >> 5;
    const int w    = t & 31;
    const int E    = w >> 2;         // e-block 0..7
    const int Dq   = w & 3;          // d-block 0..3
    const int cb   = hsub * 64;
    const int e0   = cb + E * 8;
    const int d0   = cb + Dq * 16;

    float kvacc[8][16];
#pragma unroll
    for (int i = 0; i < 8; ++i)
#pragma unroll
        for (int j = 0; j < 16; ++j) kvacc[i][j] = 0.f;
    float ksacc[8] = {0, 0, 0, 0, 0, 0, 0, 0};

    for (int it = 0; it < 28; ++it) {
        __syncthreads();
#pragma unroll
        for (int i = 0; i < 4; ++i) {
            const int idx = t + (i << 8);            // 0..1023
            const int rr  = (idx >> 6) & 7;
            const int c   = idx & 63;
            const long grow = rowstart + it * 8 + rr;
            const __hip_bfloat16* srcp =
                ((idx < 512) ? kbuf : vbuf) + grow * 1024 + hoct * 512 + c * 8;
            bf16x8 v8 = *(const bf16x8*)srcp;
            float* dstp = (idx < 512) ? &kf[rr][c * 8] : &vf[rr][c * 8];
#pragma unroll
            for (int jj = 0; jj < 8; ++jj)
                dstp[jj] = bf2f((unsigned short)v8[jj]);
        }
        __syncthreads();
#pragma unroll
        for (int r = 0; r < 8; ++r) {
            float ke[8], vd[16];
#pragma unroll
            for (int i = 0; i < 8; ++i)  ke[i] = kf[r][e0 + i];
#pragma unroll
            for (int j = 0; j < 16; ++j) vd[j] = vf[r][d0 + j];
#pragma unroll
            for (int i = 0; i < 8; ++i) {
                ksacc[i] += ke[i];
#pragma unroll
                for (int j = 0; j < 16; ++j)
                    kvacc[i][j] += ke[i] * vd[j];
            }
        }
    }

    const int bh = bb * 16 + hoct * 8 + hsub;
    const int s2 = E >> 2, qd = E & 3;
    float* outp = kvp + ((long)sp * 128 + bh) * 4096 + ((s2 * 4 + Dq) * 64 + qd * 16) * 8;
#pragma unroll
    for (int fr = 0; fr < 16; ++fr)
#pragma unroll
        for (int jj = 0; jj < 8; ++jj)
            outp[fr * 8 + jj] = kvacc[jj][fr];
    if (Dq == 0) {
#pragma unroll
        for (int i = 0; i < 8; ++i)
            ksump[sp * 8192 + bh * 64 + E * 8 + i] = ksacc[i];
    }
}

// ---------------------------------------------------------------------------
// Phase 2b: reduce 14 partials; kv -> bf16 frag-order, ksum -> fp32.
// ---------------------------------------------------------------------------
__global__ __launch_bounds__(256)
void reduce_kv_kernel(const float* __restrict__ kvp, const float* __restrict__ ksump,
                      unsigned short* __restrict__ kvb, float* __restrict__ ksum)
{
    const int idx = blockIdx.x * 256 + threadIdx.x;
    if (idx < 128 * 4096) {
        float a = 0.f;
#pragma unroll
        for (int s = 0; s < 14; ++s) a += kvp[(long)s * 128 * 4096 + idx];
        kvb[idx] = f2bf(a);
    } else {
        const int j = idx - 128 * 4096;
        if (j < 128 * 64) {
            float a = 0.f;
#pragma unroll
            for (int s = 0; s < 14; ++s) a += ksump[s * 8192 + j];
            ksum[j] = a;
        }
    }
}

// ---------------------------------------------------------------------------
// Phase 3: out2 = (q @ kv) * z via MFMA (K=64). Block = 64 rows x 64 d, one h.
// kv read as pre-packed B-fragments (one coalesced dwordx4 per frag).
// ---------------------------------------------------------------------------
__global__ __launch_bounds__(256)
void attn_out_kernel(const __hip_bfloat16* __restrict__ qbuf,
                     const unsigned short* __restrict__ kvb,  // [128][4096] frag-order
                     const float* __restrict__ ksum,          // [128][64]
                     __hip_bfloat16* __restrict__ out2)
{
    __shared__ __attribute__((aligned(16))) unsigned short qs[64][64];
    __shared__ float kss[64];
    __shared__ float zs[64];
    const int t   = threadIdx.x;
    const int bid = blockIdx.x;
    const int mc  = bid % 49;
    const int h   = (bid / 49) & 15;
    const int bb  = bid / 784;
    const long bh = bb * 16 + h;
    const long mbase = (long)bb * 3136 + mc * 64;

#pragma unroll
    for (int i = 0; i < 2; ++i) {
        const int idx = t + (i << 8);
        const int row = idx >> 3;
        const int c   = idx & 7;
        *(bf16x8*)&qs[row][c * 8] =
            *(const bf16x8*)(qbuf + (mbase + row) * 1024 + h * 64 + c * 8);
    }
    if (t < 64) kss[t] = ksum[bh * 64 + t];
    __syncthreads();
    if (t < 64) {
        float p = 0.f;
#pragma unroll
        for (int e = 0; e < 64; ++e) p += bf2f(qs[t][e]) * kss[e];
        zs[t] = 1.f / (p + 1e-6f);
    }
    __syncthreads();

    const int lane = t & 63;
    const int wv   = t >> 6;
    const int fr   = lane & 15;
    const int qd   = lane >> 4;

    bf16x8 bfv[2][4];
#pragma unroll
    for (int s2 = 0; s2 < 2; ++s2)
#pragma unroll
        for (int j = 0; j < 4; ++j)
            bfv[s2][j] = *(const bf16x8*)(kvb + bh * 4096 + ((s2 * 4 + j) * 64 + lane) * 8);

    const bf16x8 af0 = *(const bf16x8*)&qs[wv * 16 + fr][qd * 8];
    const bf16x8 af1 = *(const bf16x8*)&qs[wv * 16 + fr][32 + qd * 8];

    float zr[4];
#pragma unroll
    for (int r = 0; r < 4; ++r) zr[r] = zs[wv * 16 + qd * 4 + r];

#pragma unroll
    for (int j = 0; j < 4; ++j) {
        f32x4 acc = {};
        acc = __builtin_amdgcn_mfma_f32_16x16x32_bf16(af0, bfv[0][j], acc, 0, 0, 0);
        acc = __builtin_amdgcn_mfma_f32_16x16x32_bf16(af1, bfv[1][j], acc, 0, 0, 0);
#pragma unroll
        for (int r = 0; r < 4; ++r) {
            const long m = mbase + wv * 16 + qd * 4 + r;
            out2[m * 1024 + h * 64 + j * 16 + fr] = __float2bfloat16(acc[r] * zr[r]);
        }
    }
}

// ---------------------------------------------------------------------------
extern "C" void kernel_launch(void* const* d_in, const int* in_sizes, int n_in,
                              void* d_out, int out_size, void* d_ws, size_t ws_size,
                              hipStream_t stream)
{
    const float* x      = (const float*)d_in[0];
    const float* w_qkv  = (const float*)d_in[1];
    const float* w_proj = (const float*)d_in[2];
    const float* b_proj = (const float*)d_in[3];
    float* out = (float*)d_out;

    const long M = 25088;  // 128*196
    char* ws = (char*)d_ws;
    size_t off = 0;
    auto alloc = [&](size_t bytes) {
        char* p = ws + off;
        off += (bytes + 255) & ~(size_t)255;
        return p;
    };
    // ws (~112 MB): xb region reused as kvp/ksump after QKV GEMM consumes xb.
    char* xb_region = alloc(M * 1024 * 2);                 // 51.4 MB
    unsigned short* xb     = (unsigned short*)xb_region;
    float*          kvp    = (float*)xb_region;            // alias: 14*128*4096*4 = 29.4 MB
    float*          ksump  = (float*)(xb_region + (size_t)14 * 128 * 4096 * 4);
    unsigned short* wqkvb  = (unsigned short*)alloc((size_t)3072 * 1024 * 2);
    unsigned short* wprojb = (unsigned short*)alloc((size_t)1024 * 1024 * 2);
    unsigned short* vbuf   = (unsigned short*)alloc(M * 1024 * 2);
    unsigned short* kvb    = (unsigned short*)alloc((size_t)128 * 4096 * 2);
    float*          ksumr  = (float*)alloc((size_t)128 * 64 * 4);
    // d_out (103 MB) hosts qbuf+kbuf (both dead before final GEMM writes it).
    __hip_bfloat16* qbuf = (__hip_bfloat16*)d_out;
    __hip_bfloat16* kbuf = qbuf + M * 1024;
    __hip_bfloat16* out2 = (__hip_bfloat16*)vbuf;  // v dead after phase 2

    // 0) bf16 conversions (element counts all divisible by 2048)
    cvt_kernel<<<12544, 256, 0, stream>>>(x, xb);
    cvt_kernel<<<1536, 256, 0, stream>>>(w_qkv, wqkvb);
    cvt_kernel<<<512, 256, 0, stream>>>(w_proj, wprojb);
    // 1) qkv GEMM (256^2 8-phase), fused relu+0.125, scatter q/k/v
    gemm_bt_kernel<0><<<98 * 12, 512, 0, stream>>>(
        xb, wqkvb, qbuf, kbuf, (__hip_bfloat16*)vbuf, nullptr, nullptr);
    // 2) kv/ksum partials (frag-ordered)
    kv_partial_kernel<<<224, 256, 0, stream>>>(kbuf, (const __hip_bfloat16*)vbuf, kvp, ksump);
    // 2b) reduce -> kvb bf16 + ksum fp32
    reduce_kv_kernel<<<2080, 256, 0, stream>>>(kvp, ksump, kvb, ksumr);
    // 3) out2 = (q @ kv) * z   (MFMA, K=64)
    attn_out_kernel<<<8 * 16 * 49, 256, 0, stream>>>(qbuf, kvb, ksumr, out2);
    // 4) out = out2 @ w_proj^T + bias (256^2 8-phase)
    gemm_bt_kernel<1><<<98 * 4, 512, 0, stream>>>(
        (const unsigned short*)out2, wprojb, nullptr, nullptr, nullptr, out, b_proj);
}